// Round 4
// baseline (1132.761 us; speedup 1.0000x reference)
//
#include <hip/hip_runtime.h>

// MultiHead_Attn: B=8, S=1024, E=512, H=8.  fp32 I/O, fp16 MFMA internal.
//
// KEY SEMANTIC (raw torch-style .view): (q@Wq^T).reshape(b,8,1024,512) splits
// the SEQUENCE axis: head h = proj rows s in [h*128,(h+1)*128), flattened as
// s_new=(s%128)*8+(n>>9), e_new=n&511.  So each (b,h) head matrix is a
// CONTIGUOUS (1024x512) chunk of the natural row-major proj output.
// Output side: f.transpose(0,2,1,3).reshape -> f_full[b, s_new, h*512+e_new]
// (conventional column split) -> split-K out-projection over head groups.
//
// Head-group pipeline (HG heads/group, 8/HG sequential groups reuse scratch):
//   Qp,Kp = proj rows [g*HG*128,(g+1)*HG*128) per batch, natural layout (fp16)
//   Vt    = same proj, epilogue-transposed per head: [z][e_new][s_new]  (fp16)
//   E     = Qp_z @ Kp_z^T per z=(b,hl), causal tile-skip                (fp16)
//   P     = softmax(mask(E)/8) in-place
//   f     = P@V (k-limited) -> f[(b,s_new)][hl*512+e_new]               (fp16)
//   out  += f@Wo_g^T (+bo on first group)                               (fp32)
//
// Scratch fp16 (zc=8*HG): Qp,Kp,Vt,f = zc*524288 each; E = zc*1048576.
// Bytes = zc*6291456: HG=2 -> 96 MiB, HG=1 -> 48 MiB. HG picked from ws_size.

typedef _Float16 half8 __attribute__((ext_vector_type(8)));
typedef _Float16 half4v __attribute__((ext_vector_type(4)));
typedef float f32x4 __attribute__((ext_vector_type(4)));

// ---------------- staging: global -> LDS (128 rows x 32 k, fp16) ------------
__device__ __forceinline__ void stage_f16(const char* base, int ld, int r0, int k0,
                                          _Float16* lds) {
  int row = (int)threadIdx.x >> 1, part = (int)threadIdx.x & 1;
  const _Float16* src = (const _Float16*)base + (size_t)(r0 + row) * ld + k0 + part * 16;
  half8 h0 = *(const half8*)src;
  half8 h1 = *(const half8*)(src + 8);
  _Float16* d = lds + row * 32 + part * 16;
  *(half8*)d = h0;
  *(half8*)(d + 8) = h1;
}

__device__ __forceinline__ void stage_f32(const char* base, int ld, int r0, int k0,
                                          _Float16* lds) {
  int row = (int)threadIdx.x >> 1, part = (int)threadIdx.x & 1;
  const float* src = (const float*)base + (size_t)(r0 + row) * ld + k0 + part * 16;
  float4 v0 = ((const float4*)src)[0];
  float4 v1 = ((const float4*)src)[1];
  float4 v2 = ((const float4*)src)[2];
  float4 v3 = ((const float4*)src)[3];
  half8 h0, h1;
  h0[0] = (_Float16)v0.x; h0[1] = (_Float16)v0.y; h0[2] = (_Float16)v0.z; h0[3] = (_Float16)v0.w;
  h0[4] = (_Float16)v1.x; h0[5] = (_Float16)v1.y; h0[6] = (_Float16)v1.z; h0[7] = (_Float16)v1.w;
  h1[0] = (_Float16)v2.x; h1[1] = (_Float16)v2.y; h1[2] = (_Float16)v2.z; h1[3] = (_Float16)v2.w;
  h1[4] = (_Float16)v3.x; h1[5] = (_Float16)v3.y; h1[6] = (_Float16)v3.z; h1[7] = (_Float16)v3.w;
  _Float16* d = lds + row * 32 + part * 16;
  *(half8*)d = h0;
  *(half8*)(d + 8) = h1;
}

// ---------------- generic B^T GEMM: C[m,n] = sum_k A[m,k]*B[n,k] ------------
// CMODE 0: row-major, cOff = z*sC, leading dim ldc.
// CMODE 2: V-proj reshape-transpose: m in [0,HG*128), n in [0,4096):
//          hl=m>>7, s_new=(m&127)*8+(n>>9), e_new=n&511,
//          off = (z*HG+hl)*524288 + e_new*1024 + s_new   (fp16 scalar stores)
// CMODE 3: PV out: cOff = (z/HG)*1024*ldc + (z%HG)*512.
// AF32/BF32: operand fp32 (convert in staging) vs fp16 scratch.
// CF32: fp32 C. BIAS: +bias[n]. CACC: C += (fp32 rmw). CAUSAL: skip j0>i0.
// KLIM: kmax = min(K, i0+128).
template <int CMODE, int HG, bool AF32, bool BF32, bool CF32, bool BIAS, bool CACC,
          bool CAUSAL, bool KLIM>
__global__ __launch_bounds__(256) void gemm_bt(const void* __restrict__ Ap,
                                               const void* __restrict__ Bp,
                                               void* __restrict__ Cp,
                                               const float* __restrict__ bias,
                                               int tilesN, int K, int lda, int ldb, int ldc,
                                               long sA, long sB, long sC) {
  int i0 = ((int)blockIdx.x / tilesN) * 128;
  int j0 = ((int)blockIdx.x % tilesN) * 128;
  if (CAUSAL && j0 > i0) return;  // tile fully above diagonal: masked, never used
  int z = (int)blockIdx.y;
  const char* Ab = (const char*)Ap + (size_t)z * (size_t)sA * (AF32 ? 4 : 2);
  const char* Bb = (const char*)Bp + (size_t)z * (size_t)sB * (BF32 ? 4 : 2);
  size_t cOff = 0;
  if (CMODE == 0) cOff = (size_t)z * (size_t)sC;
  if (CMODE == 3) cOff = (size_t)(z / HG) * ((size_t)1024 * ldc) + (size_t)(z % HG) * 512;

  __shared__ __align__(16) _Float16 As[128 * 32];
  __shared__ __align__(16) _Float16 Bs[128 * 32];

  int kmax = K;
  if (KLIM) { int kl = i0 + 128; kmax = kl < K ? kl : K; }

  int w = (int)threadIdx.x >> 6;
  int lane = (int)threadIdx.x & 63;
  int wr = (w >> 1) * 64, wc = (w & 1) * 64;
  int lr = lane & 15, lk = (lane >> 4) * 8;

  f32x4 acc[4][4] = {};

  for (int k0 = 0; k0 < kmax; k0 += 32) {
    __syncthreads();  // previous iteration's frag reads complete
    if (AF32) stage_f32(Ab, lda, i0, k0, As); else stage_f16(Ab, lda, i0, k0, As);
    if (BF32) stage_f32(Bb, ldb, j0, k0, Bs); else stage_f16(Bb, ldb, j0, k0, Bs);
    __syncthreads();  // LDS tiles visible

    half8 a[4], b[4];
#pragma unroll
    for (int mi = 0; mi < 4; mi++)
      a[mi] = *(half8*)&As[(wr + mi * 16 + lr) * 32 + lk];
#pragma unroll
    for (int ni = 0; ni < 4; ni++)
      b[ni] = *(half8*)&Bs[(wc + ni * 16 + lr) * 32 + lk];
#pragma unroll
    for (int mi = 0; mi < 4; mi++)
#pragma unroll
      for (int ni = 0; ni < 4; ni++)
        acc[mi][ni] = __builtin_amdgcn_mfma_f32_16x16x32_f16(a[mi], b[ni], acc[mi][ni], 0, 0, 0);
  }

  // epilogue: C/D layout col=lane&15, row=(lane>>4)*4+reg  [m89/m91 verified]
  int r0 = (lane >> 4) * 4, col = lane & 15;
#pragma unroll
  for (int mi = 0; mi < 4; mi++) {
#pragma unroll
    for (int ni = 0; ni < 4; ni++) {
      int gcol = j0 + wc + ni * 16 + col;
      int growb = i0 + wr + mi * 16 + r0;
      if (CMODE == 2) {
        // head h = row block (m>>7); s_new=(m&127)*8+(n>>9); e_new=n&511
        int hl = growb >> 7;  // 4-row group never crosses a 128 boundary
        size_t zbase = ((size_t)z * HG + hl) * 524288 + (size_t)(gcol & 511) * 1024;
        int sn0 = (growb & 127) * 8 + (gcol >> 9);
#pragma unroll
        for (int r = 0; r < 4; r++)
          ((_Float16*)Cp)[zbase + sn0 + r * 8] = (_Float16)acc[mi][ni][r];
      } else {
        float bb = BIAS ? bias[gcol] : 0.0f;
#pragma unroll
        for (int r = 0; r < 4; r++) {
          int grow = growb + r;
          size_t off = cOff + (size_t)grow * ldc + gcol;
          float v = acc[mi][ni][r] + bb;
          if (CF32) {
            if (CACC) v += ((const float*)Cp)[off];
            ((float*)Cp)[off] = v;
          } else {
            ((_Float16*)Cp)[off] = (_Float16)v;
          }
        }
      }
    }
  }
}

// ---------------- row softmax, in-place E -> P (fp16) -----------------------
// One wave per row. logits: valid (j<=i): x/8 ; invalid: -inf-equivalent.
__global__ __launch_bounds__(256) void softmax_rows(void* __restrict__ Ep) {
  int R = (int)blockIdx.x * 4 + ((int)threadIdx.x >> 6);
  int lane = (int)threadIdx.x & 63;
  int i = R & 1023;  // query position (s_new) within head
  _Float16* row = (_Float16*)Ep + (size_t)R * 1024;
  float x[16];
  float m = -3.0e38f;
#pragma unroll
  for (int t = 0; t < 4; t++) {
    int j0 = t * 256 + lane * 4;
    half4v h = *(const half4v*)(row + j0);
#pragma unroll
    for (int c = 0; c < 4; c++) {
      float v = (j0 + c <= i) ? (float)h[c] * 0.125f : -3.0e38f;
      x[t * 4 + c] = v;
      m = fmaxf(m, v);
    }
  }
#pragma unroll
  for (int s = 32; s > 0; s >>= 1) m = fmaxf(m, __shfl_xor(m, s, 64));
  float p[16];
  float sum = 0.0f;
#pragma unroll
  for (int u = 0; u < 16; u++) {
    p[u] = exp2f((x[u] - m) * 1.44269504f);  // masked -> exp2(-huge) = 0
    sum += p[u];
  }
#pragma unroll
  for (int s = 32; s > 0; s >>= 1) sum += __shfl_xor(sum, s, 64);
  float inv = 1.0f / sum;
#pragma unroll
  for (int t = 0; t < 4; t++) {
    int j0 = t * 256 + lane * 4;
    half4v h;
#pragma unroll
    for (int c = 0; c < 4; c++) h[c] = (_Float16)(p[t * 4 + c] * inv);
    *(half4v*)(row + j0) = h;
  }
}

// ---------------------------------------------------------------------------
template <int HG>
static void run_pipeline(const float* q_in, const float* k_in, const float* v_in,
                         const float* Wq, const float* Wk, const float* Wv,
                         const float* Wo, const float* bo, float* out, char* ws,
                         hipStream_t stream) {
  const int NG = 8 / HG;            // sequential groups
  const size_t zc = 8 * HG;         // z-slices (b, h_local) per group
  _Float16* Qp = (_Float16*)ws;                 // zc*524288 (natural [b][HG*128][4096])
  _Float16* Kp = Qp + zc * 524288;
  _Float16* Vt = Kp + zc * 524288;              // [z][e_new][s_new]
  _Float16* E = Vt + zc * 524288;               // zc*1048576
  _Float16* f = E + zc * 1048576;               // zc*524288 = [8192][HG*512]
  dim3 blk(256);

  for (int g = 0; g < NG; g++) {
    // group g covers heads [g*HG,(g+1)*HG) = proj rows [g*HG*128,(g+1)*HG*128) per batch
    const float* qg = q_in + (size_t)g * HG * 128 * 512;
    const float* kg = k_in + (size_t)g * HG * 128 * 512;
    const float* vg = v_in + (size_t)g * HG * 128 * 512;
    const float* WoG = Wo + (size_t)g * HG * 512;  // k-column slice of Wo, ld 4096

    // Q/K proj: per batch z: (HG*128 x 512 fp32) @ Wq(4096x512)^T -> fp16 natural
    gemm_bt<0, HG, true, true, false, false, false, false, false>
        <<<dim3(HG * 32, 8), blk, 0, stream>>>(qg, Wq, Qp, nullptr, 32, 512, 512, 512,
                                               4096, 524288, 0, (long)HG * 524288);
    gemm_bt<0, HG, true, true, false, false, false, false, false>
        <<<dim3(HG * 32, 8), blk, 0, stream>>>(kg, Wk, Kp, nullptr, 32, 512, 512, 512,
                                               4096, 524288, 0, (long)HG * 524288);
    // V proj -> reshape-transposed [z][e_new][s_new]
    gemm_bt<2, HG, true, true, false, false, false, false, false>
        <<<dim3(HG * 32, 8), blk, 0, stream>>>(vg, Wv, Vt, nullptr, 32, 512, 512, 512,
                                               0, 524288, 0, 0);
    // energy: per z: Qp_z (1024x512) @ Kp_z^T -> E fp16 (1024x1024), causal skip
    gemm_bt<0, HG, false, false, false, false, false, true, false>
        <<<dim3(64, zc), blk, 0, stream>>>(Qp, Kp, E, nullptr, 8, 512, 512, 512, 1024,
                                           524288, 524288, 1048576);
    // softmax in-place (mask -> /8 -> softmax)
    softmax_rows<<<dim3(zc * 256, 1), blk, 0, stream>>>(E);
    // PV: per z: P (1024x1024) @ Vt_z^T -> f[(b,s_new)][hl*512+e_new], k-limited
    gemm_bt<3, HG, false, false, false, false, false, false, true>
        <<<dim3(32, zc), blk, 0, stream>>>(E, Vt, f, nullptr, 4, 1024, 1024, 1024,
                                           HG * 512, 1048576, 524288, 0);
    // out projection (split-K accumulate): out (+)= f @ WoG^T (+ bo on g==0)
    if (g == 0)
      gemm_bt<0, HG, false, true, true, true, false, false, false>
          <<<dim3(256, 1), blk, 0, stream>>>(f, WoG, out, bo, 4, HG * 512, HG * 512,
                                             4096, 512, 0, 0, 0);
    else
      gemm_bt<0, HG, false, true, true, false, true, false, false>
          <<<dim3(256, 1), blk, 0, stream>>>(f, WoG, out, bo, 4, HG * 512, HG * 512,
                                             4096, 512, 0, 0, 0);
  }
}

extern "C" void kernel_launch(void* const* d_in, const int* in_sizes, int n_in,
                              void* d_out, int out_size, void* d_ws, size_t ws_size,
                              hipStream_t stream) {
  // setup_inputs order: k, v, q, mask, Wk, Wq, Wv, Wo, bo   (fp32, per reference)
  const float* k_in = (const float*)d_in[0];
  const float* v_in = (const float*)d_in[1];
  const float* q_in = (const float*)d_in[2];
  // d_in[3] = mask: exact causal tril, handled analytically
  const float* Wk = (const float*)d_in[4];
  const float* Wq = (const float*)d_in[5];
  const float* Wv = (const float*)d_in[6];
  const float* Wo = (const float*)d_in[7];
  const float* bo = (const float*)d_in[8];
  float* out = (float*)d_out;
  char* ws = (char*)d_ws;

  // footprint: HG=2 -> 96 MiB; HG=1 -> 48 MiB
  if (ws_size >= (size_t)100663296)
    run_pipeline<2>(q_in, k_in, v_in, Wq, Wk, Wv, Wo, bo, out, ws, stream);
  else
    run_pipeline<1>(q_in, k_in, v_in, Wq, Wk, Wv, Wo, bo, out, ws, stream);
}

// Round 5
// 703.591 us; speedup vs baseline: 1.6100x; 1.6100x over previous
//
#include <hip/hip_runtime.h>

// MultiHead_Attn: B=8, S=1024, E=512, H=8.  fp32 I/O, fp16 MFMA internal.
//
// Reshape semantics (R3-verified): head (b,h) of (x@W^T).view(b,8,1024,512) is a
// CONTIGUOUS 1024x512 chunk of the natural row-major proj output (rows
// [h*128,(h+1)*128) x 4096 cols, reinterpreted).  Exploit: fold Wo in early.
//   Qp,Kp,Vp = proj (one fused dispatch, natural layout, fp16)
//   VWo_t[z][eo][s'] = Wo_h @ V_z^T          (B^T GEMM, natural operands)
//   E = Qp_z @ Kp_z^T (causal tile-skip)     (B^T GEMM)
//   P = softmax(mask(E)/8) in-place (trimmed to valid 256-chunks)
//   out += P @ VWo_t^T (causal k-limit)      (B^T GEMM, f32 atomicAdd epilogue)
// out pre-filled with bias. All fp16 operands staged via global_load_lds(16B).
// Weights pre-converted fp32->fp16 once (W16 = [Wq|Wk|Wv|Wo], 16 MiB).
//
// Scratch: W16 (16 MiB) + per-group (zc=8*HG): Qp,Kp,Vp,VWo (zc*1MiB) + E (zc*2MiB)
//   HG=4: 208 MiB, HG=2: 112 MiB, HG=1: 64 MiB.  Picked from ws_size.

typedef _Float16 half8 __attribute__((ext_vector_type(8)));
typedef _Float16 half4v __attribute__((ext_vector_type(4)));
typedef float f32x4 __attribute__((ext_vector_type(4)));

typedef __attribute__((address_space(3))) unsigned int lds_u32_t;
typedef __attribute__((address_space(1))) unsigned int g_u32_t;

__device__ __forceinline__ void glds16(const void* g, void* l) {
  // 16B per lane, LDS dest = wave-uniform base + lane*16  [m97: 517->874 TF]
  __builtin_amdgcn_global_load_lds((const g_u32_t*)g, (lds_u32_t*)l, 16, 0, 0);
}

// ---- staging: 128 rows x 32 fp16 tile -> LDS row-major [row][32] ----------
__device__ __forceinline__ void stage_glds(const _Float16* tile, int ld, _Float16* lds) {
  int w = (int)threadIdx.x >> 6, lane = (int)threadIdx.x & 63;
  int row = lane >> 2, seg = (lane & 3) * 8;  // 4 x 16B segs per 64B row
  const _Float16* g0 = tile + (size_t)(w * 32 + row) * ld + seg;
  const _Float16* g1 = tile + (size_t)(w * 32 + 16 + row) * ld + seg;
  glds16(g0, lds + (size_t)(w * 32) * 32);        // lane L lands at +L*16B = row-major
  glds16(g1, lds + (size_t)(w * 32 + 16) * 32);
}

__device__ __forceinline__ void stage_f32(const float* tile, int ld, _Float16* lds) {
  int row = (int)threadIdx.x >> 1, part = (int)threadIdx.x & 1;
  const float* src = tile + (size_t)row * ld + part * 16;
  float4 v0 = ((const float4*)src)[0];
  float4 v1 = ((const float4*)src)[1];
  float4 v2 = ((const float4*)src)[2];
  float4 v3 = ((const float4*)src)[3];
  half8 h0, h1;
  h0[0] = (_Float16)v0.x; h0[1] = (_Float16)v0.y; h0[2] = (_Float16)v0.z; h0[3] = (_Float16)v0.w;
  h0[4] = (_Float16)v1.x; h0[5] = (_Float16)v1.y; h0[6] = (_Float16)v1.z; h0[7] = (_Float16)v1.w;
  h1[0] = (_Float16)v2.x; h1[1] = (_Float16)v2.y; h1[2] = (_Float16)v2.z; h1[3] = (_Float16)v2.w;
  h1[4] = (_Float16)v3.x; h1[5] = (_Float16)v3.y; h1[6] = (_Float16)v3.z; h1[7] = (_Float16)v3.w;
  _Float16* d = lds + row * 32 + part * 16;
  *(half8*)d = h0;
  *(half8*)(d + 8) = h1;
}

// ---- generic B^T GEMM: C[m,n] = sum_k A[m,k]*B[n,k] -----------------------
// 3D grid (tiles, Y, Z); offsets: base + Y*s?y + Z*s?z (elements of own dtype).
// PROJ3: A chosen from {Ap,Ap2,Ap3} by Y (q/k/v). AF32: A fp32 (convert in
// staging); else fp16 via global_load_lds. B always fp16 via global_load_lds.
// CMODE 0: fp16 store.  CMODE 1: f32 unsafeAtomicAdd (accumulate over heads).
// CAUSAL: skip tile j0>i0.  KLIM: kmax = min(K, i0+128).
template <bool PROJ3, bool AF32, int CMODE, bool CAUSAL, bool KLIM>
__global__ __launch_bounds__(256) void gemm_bt(
    const void* __restrict__ Ap, const void* __restrict__ Ap2, const void* __restrict__ Ap3,
    const void* __restrict__ Bp, void* __restrict__ Cp,
    int tilesN, int K, int lda, int ldb, int ldc,
    long sAy, long sAz, long sBy, long sBz, long sCy, long sCz) {
  int i0 = ((int)blockIdx.x / tilesN) * 128;
  int j0 = ((int)blockIdx.x % tilesN) * 128;
  if (CAUSAL && j0 > i0) return;  // fully-masked tile, never read downstream
  int Y = (int)blockIdx.y, Z = (int)blockIdx.z;
  const void* Asel = PROJ3 ? (Y == 0 ? Ap : (Y == 1 ? Ap2 : Ap3)) : Ap;
  size_t aOff = (size_t)Y * sAy + (size_t)Z * sAz;
  const _Float16* Bb = (const _Float16*)Bp + (size_t)Y * sBy + (size_t)Z * sBz;
  size_t cOff = (size_t)Y * sCy + (size_t)Z * sCz;

  __shared__ __align__(16) _Float16 As[128 * 32];
  __shared__ __align__(16) _Float16 Bs[128 * 32];

  int kmax = K;
  if (KLIM) { int kl = i0 + 128; kmax = kl < K ? kl : K; }

  int w = (int)threadIdx.x >> 6;
  int lane = (int)threadIdx.x & 63;
  int wr = (w >> 1) * 64, wc = (w & 1) * 64;
  int lr = lane & 15, lk = (lane >> 4) * 8;

  f32x4 acc[4][4] = {};

  for (int k0 = 0; k0 < kmax; k0 += 32) {
    __syncthreads();  // previous iteration's frag reads complete
    if (AF32)
      stage_f32((const float*)Asel + aOff + (size_t)i0 * lda + k0, lda, As);
    else
      stage_glds((const _Float16*)Asel + aOff + (size_t)i0 * lda + k0, lda, As);
    stage_glds(Bb + (size_t)j0 * ldb + k0, ldb, Bs);
    __syncthreads();  // glds (vmcnt) + LDS writes drained by barrier

    half8 a[4], b[4];
#pragma unroll
    for (int mi = 0; mi < 4; mi++)
      a[mi] = *(half8*)&As[(wr + mi * 16 + lr) * 32 + lk];
#pragma unroll
    for (int ni = 0; ni < 4; ni++)
      b[ni] = *(half8*)&Bs[(wc + ni * 16 + lr) * 32 + lk];
#pragma unroll
    for (int mi = 0; mi < 4; mi++)
#pragma unroll
      for (int ni = 0; ni < 4; ni++)
        acc[mi][ni] = __builtin_amdgcn_mfma_f32_16x16x32_f16(a[mi], b[ni], acc[mi][ni], 0, 0, 0);
  }

  // epilogue: C/D layout col=lane&15, row=(lane>>4)*4+reg  [m89/m91 verified]
  int r0 = (lane >> 4) * 4, col = lane & 15;
#pragma unroll
  for (int mi = 0; mi < 4; mi++) {
#pragma unroll
    for (int ni = 0; ni < 4; ni++) {
      int gcol = j0 + wc + ni * 16 + col;
      int growb = i0 + wr + mi * 16 + r0;
#pragma unroll
      for (int r = 0; r < 4; r++) {
        size_t off = cOff + (size_t)(growb + r) * ldc + gcol;
        if (CMODE == 1)
          unsafeAtomicAdd((float*)Cp + off, acc[mi][ni][r]);
        else
          ((_Float16*)Cp)[off] = (_Float16)acc[mi][ni][r];
      }
    }
  }
}

// ---- row softmax, in-place E -> P (fp16), trimmed to valid chunks ---------
__global__ __launch_bounds__(256) void softmax_rows(void* __restrict__ Ep) {
  int R = (int)blockIdx.x * 4 + ((int)threadIdx.x >> 6);
  int lane = (int)threadIdx.x & 63;
  int i = R & 1023;          // query position within head
  int nt = (i >> 8) + 1;     // 256-chunks needed: covers k < (i&~127)+128
  _Float16* row = (_Float16*)Ep + (size_t)R * 1024;
  float x[16];
  float m = -3.0e38f;
#pragma unroll
  for (int t = 0; t < 4; t++) {
    if (t < nt) {  // wave-uniform branch
      int j0 = t * 256 + lane * 4;
      half4v h = *(const half4v*)(row + j0);
#pragma unroll
      for (int c = 0; c < 4; c++) {
        float v = (j0 + c <= i) ? (float)h[c] * 0.125f : -3.0e38f;
        x[t * 4 + c] = v;
        m = fmaxf(m, v);
      }
    }
  }
#pragma unroll
  for (int s = 32; s > 0; s >>= 1) m = fmaxf(m, __shfl_xor(m, s, 64));
  float p[16];
  float sum = 0.0f;
#pragma unroll
  for (int t = 0; t < 4; t++) {
    if (t < nt) {
#pragma unroll
      for (int c = 0; c < 4; c++) {
        p[t * 4 + c] = exp2f((x[t * 4 + c] - m) * 1.44269504f);  // masked -> 0
        sum += p[t * 4 + c];
      }
    }
  }
#pragma unroll
  for (int s = 32; s > 0; s >>= 1) sum += __shfl_xor(sum, s, 64);
  float inv = 1.0f / sum;
#pragma unroll
  for (int t = 0; t < 4; t++) {
    if (t < nt) {
      int j0 = t * 256 + lane * 4;
      half4v h;
#pragma unroll
      for (int c = 0; c < 4; c++) h[c] = (_Float16)(p[t * 4 + c] * inv);
      *(half4v*)(row + j0) = h;
    }
  }
}

// ---- weight preconvert: W16 = [Wq|Wk|Wv|Wo] fp16, 4 x 2M elements ---------
__global__ __launch_bounds__(256) void wconv(const float* __restrict__ Wq,
                                             const float* __restrict__ Wk,
                                             const float* __restrict__ Wv,
                                             const float* __restrict__ Wo,
                                             _Float16* __restrict__ W16) {
  size_t base = ((size_t)blockIdx.x * 256 + threadIdx.x) * 8;  // grid 4096 -> 8M
  int wid = (int)(base >> 21);
  size_t off = base & 2097151;
  const float* src = wid == 0 ? Wq : (wid == 1 ? Wk : (wid == 2 ? Wv : Wo));
  float4 a = *(const float4*)(src + off);
  float4 b = *(const float4*)(src + off + 4);
  half8 h;
  h[0] = (_Float16)a.x; h[1] = (_Float16)a.y; h[2] = (_Float16)a.z; h[3] = (_Float16)a.w;
  h[4] = (_Float16)b.x; h[5] = (_Float16)b.y; h[6] = (_Float16)b.z; h[7] = (_Float16)b.w;
  *(half8*)(W16 + base) = h;
}

// ---- out init: out[s][eo] = bo[eo]  (atomic accumulation base) -------------
__global__ __launch_bounds__(256) void bias_init(float* __restrict__ out,
                                                 const float* __restrict__ bo) {
  size_t idx = ((size_t)blockIdx.x * 256 + threadIdx.x) * 4;  // grid 4096 -> 4M
  *(float4*)(out + idx) = *(const float4*)(bo + (idx & 511));
}

// ---------------------------------------------------------------------------
template <int HG>
static void run_pipeline(const float* q_in, const float* k_in, const float* v_in,
                         const float* Wq, const float* Wk, const float* Wv,
                         const float* Wo, const float* bo, float* out, char* ws,
                         hipStream_t stream) {
  const int NG = 8 / HG;
  const long zc = 8 * HG;
  _Float16* W16 = (_Float16*)ws;            // 8388608 elem (16 MiB)
  _Float16* Qp = W16 + 8388608;             // zc*524288 each
  _Float16* Kp = Qp + zc * 524288;
  _Float16* Vp = Kp + zc * 524288;
  _Float16* VWo = Vp + zc * 524288;         // [z][eo][s'] 512x1024 per z
  _Float16* E = VWo + zc * 524288;          // zc*1048576
  _Float16* Wo16 = W16 + 3 * 2097152;
  dim3 blk(256);

  wconv<<<dim3(4096), blk, 0, stream>>>(Wq, Wk, Wv, Wo, W16);
  bias_init<<<dim3(4096), blk, 0, stream>>>(out, bo);

  for (int g = 0; g < NG; g++) {
    const float* qg = q_in + (size_t)g * HG * 128 * 512;
    const float* kg = k_in + (size_t)g * HG * 128 * 512;
    const float* vg = v_in + (size_t)g * HG * 128 * 512;

    // fused Q/K/V proj: Y=mat, Z=batch; C natural [mat][b][HG*128][4096]
    gemm_bt<true, true, 0, false, false><<<dim3(HG * 32, 3, 8), blk, 0, stream>>>(
        qg, kg, vg, W16, Qp, 32, 512, 512, 512, 4096,
        0, 524288, 2097152, 0, zc * 524288, (long)HG * 524288);

    // VWo_t[z][eo][s'] = Wo_h @ V_z^T : Y=hl, Z=b
    gemm_bt<false, false, 0, false, false><<<dim3(32, HG, 8), blk, 0, stream>>>(
        Wo16 + (size_t)g * HG * 512, nullptr, nullptr, Vp, VWo,
        8, 512, 4096, 512, 1024,
        512, 0, 524288, (long)HG * 524288, 524288, (long)HG * 524288);

    // energy: E_z = Qp_z @ Kp_z^T, causal tile-skip
    gemm_bt<false, false, 0, true, false><<<dim3(64, HG, 8), blk, 0, stream>>>(
        Qp, nullptr, nullptr, Kp, E, 8, 512, 512, 512, 1024,
        524288, (long)HG * 524288, 524288, (long)HG * 524288,
        1048576, (long)HG * 1048576);

    // softmax in-place (mask -> /8 -> softmax), trimmed
    softmax_rows<<<dim3(zc * 256), blk, 0, stream>>>(E);

    // out += P_z @ VWo_t_z^T  (k-limited, f32 atomic accumulate over heads)
    gemm_bt<false, false, 1, false, true><<<dim3(32, HG, 8), blk, 0, stream>>>(
        E, nullptr, nullptr, VWo, out, 4, 1024, 1024, 1024, 512,
        1048576, (long)HG * 1048576, 524288, (long)HG * 524288, 0, 524288);
  }
}

extern "C" void kernel_launch(void* const* d_in, const int* in_sizes, int n_in,
                              void* d_out, int out_size, void* d_ws, size_t ws_size,
                              hipStream_t stream) {
  // setup_inputs order: k, v, q, mask, Wk, Wq, Wv, Wo, bo   (fp32)
  const float* k_in = (const float*)d_in[0];
  const float* v_in = (const float*)d_in[1];
  const float* q_in = (const float*)d_in[2];
  // d_in[3] = mask: exact causal tril, handled analytically
  const float* Wk = (const float*)d_in[4];
  const float* Wq = (const float*)d_in[5];
  const float* Wv = (const float*)d_in[6];
  const float* Wo = (const float*)d_in[7];
  const float* bo = (const float*)d_in[8];
  float* out = (float*)d_out;
  char* ws = (char*)d_ws;

  // footprint: 16 MiB weights + zc*6 MiB group scratch
  if (ws_size >= (size_t)218103808)       // 208 MiB
    run_pipeline<4>(q_in, k_in, v_in, Wq, Wk, Wv, Wo, bo, out, ws, stream);
  else if (ws_size >= (size_t)117440512)  // 112 MiB
    run_pipeline<2>(q_in, k_in, v_in, Wq, Wk, Wv, Wo, bo, out, ws, stream);
  else                                     // 64 MiB
    run_pipeline<1>(q_in, k_in, v_in, Wq, Wk, Wv, Wo, bo, out, ws, stream);
}

// Round 6
// 632.020 us; speedup vs baseline: 1.7923x; 1.1132x over previous
//
#include <hip/hip_runtime.h>

// MultiHead_Attn: B=8, S=1024, E=512, H=8.  fp32 I/O, fp16 MFMA internal.
//
// Reshape semantics (R3-verified): head (b,h) of (x@W^T).view(b,8,1024,512) is
// a CONTIGUOUS 1024x512 chunk of the natural row-major proj output.  Wo folded
// in early:  VWo_t[z][eo][s'] = Wo_h @ V_z^T,  out += P_z @ VWo_t_z^T.
//
// Per group (HG heads, NG=8/HG groups reuse scratch):
//   in16      = fp16 copies of q/k/v group slices      (inconv, BW-bound)
//   Qp,Kp,Vp  = proj (one dispatch, C3 select)         (Vp overlaid on E)
//   VWo       = Wo_h @ V_z^T
//   E         = Qp_z @ Kp_z^T  (causal tile-skip)
//   P         = softmax(mask(E)/8) in-place (trimmed)
//   out      += P @ VWo^T  (k-limited, head-pairs accumulated in-register,
//                           f32 unsafeAtomicAdd onto bias-initialized out)
// ALL GEMM operands are fp16 staged via global_load_lds(16B)  [m97 structure].
//
// Scratch (fp16 elem): W16 8.39M | in16 3*HG*524288 | Qp,Kp,VWo zc*524288
// | E zc*1048576 (Vp overlay).  HG=4: 188 MiB, HG=2: 102 MiB, HG=1: 59 MiB.

typedef _Float16 half8 __attribute__((ext_vector_type(8)));
typedef _Float16 half4v __attribute__((ext_vector_type(4)));
typedef float f32x4 __attribute__((ext_vector_type(4)));

typedef __attribute__((address_space(3))) unsigned int lds_u32_t;
typedef __attribute__((address_space(1))) unsigned int g_u32_t;

__device__ __forceinline__ void glds16(const void* g, void* l) {
  // 16B/lane, LDS dest = wave-uniform base + lane*16  [m97: 517->874 TF]
  __builtin_amdgcn_global_load_lds((const g_u32_t*)g, (lds_u32_t*)l, 16, 0, 0);
}

// ---- stage 128 rows x 32 fp16 -> LDS row-major [row][32], via glds ---------
__device__ __forceinline__ void stage_glds(const _Float16* tile, int ld, _Float16* lds) {
  int w = (int)threadIdx.x >> 6, lane = (int)threadIdx.x & 63;
  int row = lane >> 2, seg = (lane & 3) * 8;  // 4 x 16B segments per 64B row
  const _Float16* g0 = tile + (size_t)(w * 32 + row) * ld + seg;
  const _Float16* g1 = tile + (size_t)(w * 32 + 16 + row) * ld + seg;
  glds16(g0, lds + (size_t)(w * 32) * 32);   // lane L -> +L*16B = row-major
  glds16(g1, lds + (size_t)(w * 32 + 16) * 32);
}

// ---- generic B^T GEMM: C[m,n] = sum_{h,k} A_h[m,k]*B_h[n,k] ----------------
// C3: C base selected from {C0,C1,C2} by Y (proj).  CMODE 0: fp16 store;
// CMODE 1: f32 unsafeAtomicAdd.  CAUSAL: skip tile j0>i0.  KLIM: kmax=min(K,i0+128).
// HL: inner head-loop count (A/B advance by sAh/sBh per step).
template <int C3, int CMODE, bool CAUSAL, bool KLIM, int HL>
__global__ __launch_bounds__(256) void gemm_bt(
    const _Float16* __restrict__ Ap, const _Float16* __restrict__ Bp,
    void* __restrict__ C0, void* __restrict__ C1, void* __restrict__ C2,
    int tilesN, int K, int lda, int ldb, int ldc,
    long sAy, long sAz, long sAh, long sBy, long sBz, long sBh,
    long sCy, long sCz) {
  int i0 = ((int)blockIdx.x / tilesN) * 128;
  int j0 = ((int)blockIdx.x % tilesN) * 128;
  if (CAUSAL && j0 > i0) return;  // fully-masked tile, never read downstream
  int Y = (int)blockIdx.y, Z = (int)blockIdx.z;
  const _Float16* Ab = Ap + (size_t)Y * sAy + (size_t)Z * sAz + (size_t)i0 * lda;
  const _Float16* Bb = Bp + (size_t)Y * sBy + (size_t)Z * sBz + (size_t)j0 * ldb;
  void* Cb = C3 ? (Y == 0 ? C0 : (Y == 1 ? C1 : C2)) : C0;
  size_t cOff = (C3 ? 0 : (size_t)Y * sCy) + (size_t)Z * sCz;

  __shared__ __align__(16) _Float16 As[128 * 32];
  __shared__ __align__(16) _Float16 Bs[128 * 32];

  int kmax = K;
  if (KLIM) { int kl = i0 + 128; kmax = kl < K ? kl : K; }

  int w = (int)threadIdx.x >> 6;
  int lane = (int)threadIdx.x & 63;
  int wr = (w >> 1) * 64, wc = (w & 1) * 64;
  int lr = lane & 15, lk = (lane >> 4) * 8;

  f32x4 acc[4][4] = {};

  for (int h = 0; h < HL; h++) {
    const _Float16* At = Ab + (size_t)h * sAh;
    const _Float16* Bt = Bb + (size_t)h * sBh;
    for (int k0 = 0; k0 < kmax; k0 += 32) {
      __syncthreads();  // previous iteration's frag reads complete
      stage_glds(At + k0, lda, As);
      stage_glds(Bt + k0, ldb, Bs);
      __syncthreads();  // vmcnt drained by barrier -> tiles visible

      half8 a[4], b[4];
#pragma unroll
      for (int mi = 0; mi < 4; mi++)
        a[mi] = *(half8*)&As[(wr + mi * 16 + lr) * 32 + lk];
#pragma unroll
      for (int ni = 0; ni < 4; ni++)
        b[ni] = *(half8*)&Bs[(wc + ni * 16 + lr) * 32 + lk];
#pragma unroll
      for (int mi = 0; mi < 4; mi++)
#pragma unroll
        for (int ni = 0; ni < 4; ni++)
          acc[mi][ni] = __builtin_amdgcn_mfma_f32_16x16x32_f16(a[mi], b[ni], acc[mi][ni], 0, 0, 0);
    }
  }

  // epilogue: C/D layout col=lane&15, row=(lane>>4)*4+reg  [m89/m91 verified]
  int r0 = (lane >> 4) * 4, col = lane & 15;
#pragma unroll
  for (int mi = 0; mi < 4; mi++) {
#pragma unroll
    for (int ni = 0; ni < 4; ni++) {
      int gcol = j0 + wc + ni * 16 + col;
      int growb = i0 + wr + mi * 16 + r0;
#pragma unroll
      for (int r = 0; r < 4; r++) {
        size_t off = cOff + (size_t)(growb + r) * ldc + gcol;
        if (CMODE == 1)
          unsafeAtomicAdd((float*)Cb + off, acc[mi][ni][r]);
        else
          ((_Float16*)Cb)[off] = (_Float16)acc[mi][ni][r];
      }
    }
  }
}

// ---- row softmax, in-place E -> P (fp16), trimmed to valid 256-chunks ------
__global__ __launch_bounds__(256) void softmax_rows(void* __restrict__ Ep) {
  int R = (int)blockIdx.x * 4 + ((int)threadIdx.x >> 6);
  int lane = (int)threadIdx.x & 63;
  int i = R & 1023;          // query position within head
  int nt = (i >> 8) + 1;     // 256-chunks covering k < (i&~127)+128
  _Float16* row = (_Float16*)Ep + (size_t)R * 1024;
  float x[16];
  float m = -3.0e38f;
#pragma unroll
  for (int t = 0; t < 4; t++) {
    if (t < nt) {  // wave-uniform
      int j0 = t * 256 + lane * 4;
      half4v h = *(const half4v*)(row + j0);
#pragma unroll
      for (int c = 0; c < 4; c++) {
        float v = (j0 + c <= i) ? (float)h[c] * 0.125f : -3.0e38f;
        x[t * 4 + c] = v;
        m = fmaxf(m, v);
      }
    }
  }
#pragma unroll
  for (int s = 32; s > 0; s >>= 1) m = fmaxf(m, __shfl_xor(m, s, 64));
  float p[16];
  float sum = 0.0f;
#pragma unroll
  for (int t = 0; t < 4; t++) {
    if (t < nt) {
#pragma unroll
      for (int c = 0; c < 4; c++) {
        p[t * 4 + c] = exp2f((x[t * 4 + c] - m) * 1.44269504f);  // masked -> 0
        sum += p[t * 4 + c];
      }
    }
  }
#pragma unroll
  for (int s = 32; s > 0; s >>= 1) sum += __shfl_xor(sum, s, 64);
  float inv = 1.0f / sum;
#pragma unroll
  for (int t = 0; t < 4; t++) {
    if (t < nt) {
      int j0 = t * 256 + lane * 4;
      half4v h;
#pragma unroll
      for (int c = 0; c < 4; c++) h[c] = (_Float16)(p[t * 4 + c] * inv);
      *(half4v*)(row + j0) = h;
    }
  }
}

// ---- weight preconvert: W16 = [Wq|Wk|Wv|Wo] fp16 ---------------------------
__global__ __launch_bounds__(256) void wconv(const float* __restrict__ Wq,
                                             const float* __restrict__ Wk,
                                             const float* __restrict__ Wv,
                                             const float* __restrict__ Wo,
                                             _Float16* __restrict__ W16) {
  size_t base = ((size_t)blockIdx.x * 256 + threadIdx.x) * 8;  // grid 4096 -> 8M
  int wid = (int)(base >> 21);
  size_t off = base & 2097151;
  const float* src = wid == 0 ? Wq : (wid == 1 ? Wk : (wid == 2 ? Wv : Wo));
  float4 a = *(const float4*)(src + off);
  float4 b = *(const float4*)(src + off + 4);
  half8 h;
  h[0] = (_Float16)a.x; h[1] = (_Float16)a.y; h[2] = (_Float16)a.z; h[3] = (_Float16)a.w;
  h[4] = (_Float16)b.x; h[5] = (_Float16)b.y; h[6] = (_Float16)b.z; h[7] = (_Float16)b.w;
  *(half8*)(W16 + base) = h;
}

// ---- input group-slice preconvert: in16[tensor][b][HG*128*512] fp16 --------
template <int HG>
__global__ __launch_bounds__(256) void inconv(const float* __restrict__ q,
                                              const float* __restrict__ k,
                                              const float* __restrict__ v,
                                              _Float16* __restrict__ dst) {
  int Y = (int)blockIdx.y;
  size_t base = ((size_t)blockIdx.x * 256 + threadIdx.x) * 8;  // < HG*524288
  size_t b = base / (HG * 65536);                              // constexpr shift
  size_t within = base - b * (HG * 65536);
  const float* src = (Y == 0 ? q : (Y == 1 ? k : v)) + b * 524288 + within;
  float4 a = ((const float4*)src)[0];
  float4 c = ((const float4*)src)[1];
  half8 h;
  h[0] = (_Float16)a.x; h[1] = (_Float16)a.y; h[2] = (_Float16)a.z; h[3] = (_Float16)a.w;
  h[4] = (_Float16)c.x; h[5] = (_Float16)c.y; h[6] = (_Float16)c.z; h[7] = (_Float16)c.w;
  *(half8*)(dst + (size_t)Y * HG * 524288 + base) = h;
}

// ---- out init: out[s][eo] = bo[eo]  (base for atomic accumulation) ---------
__global__ __launch_bounds__(256) void bias_init(float* __restrict__ out,
                                                 const float* __restrict__ bo) {
  size_t idx = ((size_t)blockIdx.x * 256 + threadIdx.x) * 4;  // grid 4096 -> 4M
  *(float4*)(out + idx) = *(const float4*)(bo + (idx & 511));
}

// ---------------------------------------------------------------------------
template <int HG>
static void run_pipeline(const float* q_in, const float* k_in, const float* v_in,
                         const float* Wq, const float* Wk, const float* Wv,
                         const float* Wo, const float* bo, float* out, char* ws,
                         hipStream_t stream) {
  const int NG = 8 / HG;
  const long zc = 8 * HG;
  _Float16* W16 = (_Float16*)ws;                 // 8,388,608
  _Float16* in16 = W16 + 8388608;                // 3*HG*524288
  _Float16* Qp = in16 + 3L * HG * 524288;        // zc*524288 each
  _Float16* Kp = Qp + zc * 524288;
  _Float16* VWo = Kp + zc * 524288;
  _Float16* E = VWo + zc * 524288;               // zc*1048576
  _Float16* Vp = E;                              // overlay: dead before E written
  _Float16* Wo16 = W16 + 3 * 2097152;
  dim3 blk(256);

  wconv<<<dim3(4096), blk, 0, stream>>>(Wq, Wk, Wv, Wo, W16);
  bias_init<<<dim3(4096), blk, 0, stream>>>(out, bo);

  constexpr int YS = (HG > 1) ? HG / 2 : 1;  // PV y-split (head pairs)
  constexpr int HL = HG / YS;

  for (int g = 0; g < NG; g++) {
    // fp16 conversion of this group's q/k/v row-slices
    inconv<HG><<<dim3(HG * 256, 3), blk, 0, stream>>>(
        q_in + (size_t)g * HG * 65536, k_in + (size_t)g * HG * 65536,
        v_in + (size_t)g * HG * 65536, in16);

    // fused Q/K/V proj: Y=tensor, Z=batch; C3 select {Qp,Kp,Vp}
    gemm_bt<1, 0, false, false, 1><<<dim3(HG * 32, 3, 8), blk, 0, stream>>>(
        in16, W16, Qp, Kp, Vp, 32, 512, 512, 512, 4096,
        (long)HG * 524288, (long)HG * 65536, 0, 2097152, 0, 0,
        0, (long)HG * 524288);

    // VWo_t[z][eo][s'] = Wo_h @ V_z^T : Y=hl, Z=b
    gemm_bt<0, 0, false, false, 1><<<dim3(32, HG, 8), blk, 0, stream>>>(
        Wo16 + (size_t)g * HG * 512, Vp, VWo, nullptr, nullptr,
        8, 512, 4096, 512, 1024,
        512, 0, 0, 524288, (long)HG * 524288, 0,
        524288, (long)HG * 524288);

    // energy: E_z = Qp_z @ Kp_z^T, causal tile-skip
    gemm_bt<0, 0, true, false, 1><<<dim3(64, HG, 8), blk, 0, stream>>>(
        Qp, Kp, E, nullptr, nullptr, 8, 512, 512, 512, 1024,
        524288, (long)HG * 524288, 0, 524288, (long)HG * 524288, 0,
        1048576, (long)HG * 1048576);

    // softmax in-place (mask -> /8 -> softmax), trimmed
    softmax_rows<<<dim3(zc * 256), blk, 0, stream>>>(E);

    // out += P_z @ VWo_t_z^T : Y=head-pair, HL heads in-register, k-limited
    gemm_bt<0, 1, false, true, HL><<<dim3(32, YS, 8), blk, 0, stream>>>(
        E, VWo, out, nullptr, nullptr, 4, 1024, 1024, 1024, 512,
        (long)HL * 1048576, (long)HG * 1048576, 1048576,
        (long)HL * 524288, (long)HG * 524288, 524288,
        0, 524288);
  }
}

extern "C" void kernel_launch(void* const* d_in, const int* in_sizes, int n_in,
                              void* d_out, int out_size, void* d_ws, size_t ws_size,
                              hipStream_t stream) {
  // setup_inputs order: k, v, q, mask, Wk, Wq, Wv, Wo, bo   (fp32)
  const float* k_in = (const float*)d_in[0];
  const float* v_in = (const float*)d_in[1];
  const float* q_in = (const float*)d_in[2];
  // d_in[3] = mask: exact causal tril, handled analytically
  const float* Wk = (const float*)d_in[4];
  const float* Wq = (const float*)d_in[5];
  const float* Wv = (const float*)d_in[6];
  const float* Wo = (const float*)d_in[7];
  const float* bo = (const float*)d_in[8];
  float* out = (float*)d_out;
  char* ws = (char*)d_ws;

  // exact footprints: HG=4 -> 197,132,288 B; HG=2 -> 106,954,752; HG=1 -> 61,865,984
  if (ws_size >= (size_t)197132288)
    run_pipeline<4>(q_in, k_in, v_in, Wq, Wk, Wv, Wo, bo, out, ws, stream);
  else if (ws_size >= (size_t)106954752)
    run_pipeline<2>(q_in, k_in, v_in, Wq, Wk, Wv, Wo, bo, out, ws, stream);
  else
    run_pipeline<1>(q_in, k_in, v_in, Wq, Wk, Wv, Wo, bo, out, ws, stream);
}

// Round 8
// 572.257 us; speedup vs baseline: 1.9795x; 1.1044x over previous
//
#include <hip/hip_runtime.h>

// MultiHead_Attn: B=8, S=1024, E=512, H=8.  fp32 I/O, fp16 MFMA internal.
//
// Reshape semantics (R3-verified): head (b,h) of (x@W^T).view(b,8,1024,512) is
// a CONTIGUOUS 1024x512 chunk of the natural row-major proj output.  Wo folded
// in early:  VWo_t[z][eo][s'] = Wo_h @ V_z^T,  out += P_z @ VWo_t_z^T.
//
// R8: BK=64 (2x32 panels, half the barriers), LDS-transpose vectorized fp16
// epilogue, triangular energy grid.  VWo and energy are SEPARATE dispatches:
// Vp is overlaid on E, so VWo (reads Vp) must stream-complete before energy
// (writes E).  [R7 merged them -> intra-dispatch race -> absmax 68]
// Per group: inconv -> proj(QKV) -> VWo -> energy -> softmax -> PV.
// ALL GEMM operands staged via global_load_lds(16B)  [m97 structure].
//
// Scratch (fp16 el): W16 8.39M | in16 3*HG*524288 | Qp,Kp,VWo zc*524288
// | E zc*1048576 (Vp overlay).  HG=4: 188 MiB, HG=2: 102 MiB, HG=1: 59 MiB.

typedef _Float16 half8 __attribute__((ext_vector_type(8)));
typedef _Float16 half4v __attribute__((ext_vector_type(4)));
typedef float f32x4 __attribute__((ext_vector_type(4)));

typedef __attribute__((address_space(3))) unsigned int lds_u32_t;
typedef __attribute__((address_space(1))) unsigned int g_u32_t;

__device__ __forceinline__ void glds16(const void* g, void* l) {
  // 16B/lane, LDS dest = wave-uniform base + lane*16  [m97: 517->874 TF]
  __builtin_amdgcn_global_load_lds((const g_u32_t*)g, (lds_u32_t*)l, 16, 0, 0);
}

// ---- GEMM core: acc += A(128xK) * B(128xK)^T, BK=64 as 2x32-col panels -----
template <int HL>
__device__ __forceinline__ void gemm_core(const _Float16* A, const _Float16* B,
                                          int lda, int ldb, int kmax,
                                          long sAh, long sBh,
                                          _Float16* As, _Float16* Bs,
                                          f32x4 (&acc)[4][4]) {
  int tid = (int)threadIdx.x;
  int w = tid >> 6, lane = tid & 63;
  int wr = (w >> 1) * 64, wc = (w & 1) * 64;
  int lr = lane & 15, lk = (lane >> 4) * 8;
  int srow = lane >> 2, sseg = (lane & 3) * 8;  // staging lane map

  for (int h = 0; h < HL; h++) {
    const _Float16* Ah = A + (size_t)h * sAh;
    const _Float16* Bh = B + (size_t)h * sBh;
    for (int k0 = 0; k0 < kmax; k0 += 64) {
      __syncthreads();  // previous iteration's frag reads complete
#pragma unroll
      for (int p = 0; p < 2; p++)
#pragma unroll
        for (int t = 0; t < 2; t++) {
          glds16(Ah + (size_t)(w * 32 + t * 16 + srow) * lda + k0 + p * 32 + sseg,
                 As + p * 4096 + (w * 32 + t * 16) * 32);
          glds16(Bh + (size_t)(w * 32 + t * 16 + srow) * ldb + k0 + p * 32 + sseg,
                 Bs + p * 4096 + (w * 32 + t * 16) * 32);
        }
      __syncthreads();  // vmcnt drained by barrier -> panels visible
#pragma unroll
      for (int p = 0; p < 2; p++) {
        half8 a[4], b[4];
#pragma unroll
        for (int mi = 0; mi < 4; mi++)
          a[mi] = *(half8*)&As[p * 4096 + (wr + mi * 16 + lr) * 32 + lk];
#pragma unroll
        for (int ni = 0; ni < 4; ni++)
          b[ni] = *(half8*)&Bs[p * 4096 + (wc + ni * 16 + lr) * 32 + lk];
#pragma unroll
        for (int mi = 0; mi < 4; mi++)
#pragma unroll
          for (int ni = 0; ni < 4; ni++)
            acc[mi][ni] =
                __builtin_amdgcn_mfma_f32_16x16x32_f16(a[mi], b[ni], acc[mi][ni], 0, 0, 0);
      }
    }
  }
}

// ---- fp16 epilogue: LDS transpose (stride 136) -> 16B coalesced stores -----
__device__ __forceinline__ void epilogue_f16(f32x4 (&acc)[4][4], _Float16* T,
                                             _Float16* Cp, size_t cOff,
                                             int i0, int j0, int ldc) {
  int tid = (int)threadIdx.x;
  int w = tid >> 6, lane = tid & 63;
  int wr = (w >> 1) * 64, wc = (w & 1) * 64;
  int r0 = (lane >> 4) * 4, col = lane & 15;
  __syncthreads();  // all waves done reading staging LDS
#pragma unroll
  for (int mi = 0; mi < 4; mi++)
#pragma unroll
    for (int ni = 0; ni < 4; ni++)
#pragma unroll
      for (int r = 0; r < 4; r++)
        T[(size_t)(wr + mi * 16 + r0 + r) * 136 + wc + ni * 16 + col] =
            (_Float16)acc[mi][ni][r];
  __syncthreads();
#pragma unroll
  for (int s = 0; s < 8; s++) {
    int row = w * 32 + s * 4 + (lane >> 4);
    int c8 = (lane & 15) * 8;
    half8 h = *(half8*)&T[(size_t)row * 136 + c8];
    *(half8*)(Cp + cOff + (size_t)(i0 + row) * ldc + j0 + c8) = h;
  }
}

// ---- atomic f32 epilogue (PV accumulation over heads) ----------------------
__device__ __forceinline__ void epilogue_atomic(f32x4 (&acc)[4][4], float* Cp,
                                                size_t cOff, int i0, int j0, int ldc) {
  int tid = (int)threadIdx.x;
  int w = tid >> 6, lane = tid & 63;
  int wr = (w >> 1) * 64, wc = (w & 1) * 64;
  int r0 = (lane >> 4) * 4, col = lane & 15;
#pragma unroll
  for (int mi = 0; mi < 4; mi++)
#pragma unroll
    for (int ni = 0; ni < 4; ni++)
#pragma unroll
      for (int r = 0; r < 4; r++)
        unsafeAtomicAdd(Cp + cOff + (size_t)(i0 + wr + mi * 16 + r0 + r) * ldc +
                            j0 + wc + ni * 16 + col,
                        acc[mi][ni][r]);
}

// ---- QKV projection: Y=tensor, Z=batch -------------------------------------
template <int HG>
__global__ __launch_bounds__(256) void proj_kernel(const _Float16* __restrict__ in16,
                                                   const _Float16* __restrict__ W16,
                                                   _Float16* __restrict__ Qp,
                                                   _Float16* __restrict__ Kp,
                                                   _Float16* __restrict__ Vp) {
  __shared__ __align__(16) _Float16 smem[17408];
  int x = (int)blockIdx.x, Y = (int)blockIdx.y, Z = (int)blockIdx.z;
  int i0 = (x >> 5) * 128, j0 = (x & 31) * 128;
  const _Float16* A = in16 + (size_t)Y * HG * 524288 + (size_t)Z * HG * 65536 +
                      (size_t)i0 * 512;
  const _Float16* B = W16 + (size_t)Y * 2097152 + (size_t)j0 * 512;
  _Float16* C = (Y == 0 ? Qp : (Y == 1 ? Kp : Vp));
  f32x4 acc[4][4] = {};
  gemm_core<1>(A, B, 512, 512, 512, 0, 0, smem, smem + 8192, acc);
  epilogue_f16(acc, smem, C, (size_t)Z * HG * 524288, i0, j0, 4096);
}

// ---- VWo: VWo_t[z][eo][s'] = Wo_h @ V_z^T  (reads Vp = E overlay!) ---------
template <int HG>
__global__ __launch_bounds__(256) void vwo_kernel(const _Float16* __restrict__ Vp,
                                                  const _Float16* __restrict__ WoG,
                                                  _Float16* __restrict__ VWo) {
  __shared__ __align__(16) _Float16 smem[17408];
  int x = (int)blockIdx.x, Y = (int)blockIdx.y, Z = (int)blockIdx.z;
  size_t z = (size_t)Z * HG + Y;
  int i0 = (x >> 3) * 128, j0 = (x & 7) * 128;  // i0: eo-tile, j0: s'-tile
  const _Float16* A = WoG + (size_t)Y * 512 + (size_t)i0 * 4096;
  const _Float16* B = Vp + z * 524288 + (size_t)j0 * 512;
  f32x4 acc[4][4] = {};
  gemm_core<1>(A, B, 4096, 512, 512, 0, 0, smem, smem + 8192, acc);
  epilogue_f16(acc, smem, VWo, z * 524288, i0, j0, 1024);
}

// ---- energy: E_z = Qp_z @ Kp_z^T, triangular grid (36 causal tiles) --------
template <int HG>
__global__ __launch_bounds__(256) void energy_kernel(const _Float16* __restrict__ Qp,
                                                     const _Float16* __restrict__ Kp,
                                                     _Float16* __restrict__ E) {
  __shared__ __align__(16) _Float16 smem[17408];
  int x = (int)blockIdx.x, Y = (int)blockIdx.y, Z = (int)blockIdx.z;
  size_t z = (size_t)Z * HG + Y;
  int ti = (int)((sqrtf(8.0f * x + 1.0f) - 1.0f) * 0.5f);
  if (ti * (ti + 1) / 2 > x) ti--;
  else if ((ti + 1) * (ti + 2) / 2 <= x) ti++;
  int tj = x - ti * (ti + 1) / 2;
  int i0 = ti * 128, j0 = tj * 128;
  const _Float16* A = Qp + z * 524288 + (size_t)i0 * 512;
  const _Float16* B = Kp + z * 524288 + (size_t)j0 * 512;
  f32x4 acc[4][4] = {};
  gemm_core<1>(A, B, 512, 512, 512, 0, 0, smem, smem + 8192, acc);
  epilogue_f16(acc, smem, E, z * 1048576, i0, j0, 1024);
}

// ---- PV: out += P_z @ VWo_t_z^T (k-limited, HL heads in-register) ----------
template <int HG, int HL>
__global__ __launch_bounds__(256) void pv_kernel(const _Float16* __restrict__ E,
                                                 const _Float16* __restrict__ VWo,
                                                 float* __restrict__ out) {
  __shared__ __align__(16) _Float16 smem[17408];
  int x = (int)blockIdx.x, Y = (int)blockIdx.y, Z = (int)blockIdx.z;
  int i0 = (x >> 2) * 128, j0 = (x & 3) * 128;
  int kmax = i0 + 128;  // causal: P[q][s']==0 for s'>q
  const _Float16* A = E + ((size_t)Z * HG + (size_t)Y * HL) * 1048576 + (size_t)i0 * 1024;
  const _Float16* B = VWo + ((size_t)Z * HG + (size_t)Y * HL) * 524288 + (size_t)j0 * 1024;
  f32x4 acc[4][4] = {};
  gemm_core<HL>(A, B, 1024, 1024, kmax, 1048576, 524288, smem, smem + 8192, acc);
  epilogue_atomic(acc, out, (size_t)Z * 524288, i0, j0, 512);
}

// ---- row softmax, in-place E -> P (fp16), trimmed to valid 256-chunks ------
__global__ __launch_bounds__(256) void softmax_rows(void* __restrict__ Ep) {
  int R = (int)blockIdx.x * 4 + ((int)threadIdx.x >> 6);
  int lane = (int)threadIdx.x & 63;
  int i = R & 1023;
  int nt = (i >> 8) + 1;
  _Float16* row = (_Float16*)Ep + (size_t)R * 1024;
  float x[16];
  float m = -3.0e38f;
#pragma unroll
  for (int t = 0; t < 4; t++) {
    if (t < nt) {  // wave-uniform
      int j0 = t * 256 + lane * 4;
      half4v h = *(const half4v*)(row + j0);
#pragma unroll
      for (int c = 0; c < 4; c++) {
        float v = (j0 + c <= i) ? (float)h[c] * 0.125f : -3.0e38f;
        x[t * 4 + c] = v;
        m = fmaxf(m, v);
      }
    }
  }
#pragma unroll
  for (int s = 32; s > 0; s >>= 1) m = fmaxf(m, __shfl_xor(m, s, 64));
  float p[16];
  float sum = 0.0f;
#pragma unroll
  for (int t = 0; t < 4; t++) {
    if (t < nt) {
#pragma unroll
      for (int c = 0; c < 4; c++) {
        p[t * 4 + c] = exp2f((x[t * 4 + c] - m) * 1.44269504f);
        sum += p[t * 4 + c];
      }
    }
  }
#pragma unroll
  for (int s = 32; s > 0; s >>= 1) sum += __shfl_xor(sum, s, 64);
  float inv = 1.0f / sum;
#pragma unroll
  for (int t = 0; t < 4; t++) {
    if (t < nt) {
      int j0 = t * 256 + lane * 4;
      half4v h;
#pragma unroll
      for (int c = 0; c < 4; c++) h[c] = (_Float16)(p[t * 4 + c] * inv);
      *(half4v*)(row + j0) = h;
    }
  }
}

// ---- merged weight preconvert + bias init ----------------------------------
__global__ __launch_bounds__(256) void wbconv(const float* __restrict__ Wq,
                                              const float* __restrict__ Wk,
                                              const float* __restrict__ Wv,
                                              const float* __restrict__ Wo,
                                              _Float16* __restrict__ W16,
                                              float* __restrict__ out,
                                              const float* __restrict__ bo) {
  int bx = (int)blockIdx.x;
  if (bx < 4096) {
    size_t base = ((size_t)bx * 256 + threadIdx.x) * 8;
    int wid = (int)(base >> 21);
    size_t off = base & 2097151;
    const float* src = wid == 0 ? Wq : (wid == 1 ? Wk : (wid == 2 ? Wv : Wo));
    float4 a = *(const float4*)(src + off);
    float4 b = *(const float4*)(src + off + 4);
    half8 h;
    h[0] = (_Float16)a.x; h[1] = (_Float16)a.y; h[2] = (_Float16)a.z; h[3] = (_Float16)a.w;
    h[4] = (_Float16)b.x; h[5] = (_Float16)b.y; h[6] = (_Float16)b.z; h[7] = (_Float16)b.w;
    *(half8*)(W16 + base) = h;
  } else {
    size_t idx = ((size_t)(bx - 4096) * 256 + threadIdx.x) * 4;
    *(float4*)(out + idx) = *(const float4*)(bo + (idx & 511));
  }
}

// ---- input group-slice preconvert: in16[tensor][b][HG*128*512] fp16 --------
template <int HG>
__global__ __launch_bounds__(256) void inconv(const float* __restrict__ q,
                                              const float* __restrict__ k,
                                              const float* __restrict__ v,
                                              _Float16* __restrict__ dst) {
  int Y = (int)blockIdx.y;
  size_t base = ((size_t)blockIdx.x * 256 + threadIdx.x) * 8;
  size_t b = base / (HG * 65536);
  size_t within = base - b * (HG * 65536);
  const float* src = (Y == 0 ? q : (Y == 1 ? k : v)) + b * 524288 + within;
  float4 a = ((const float4*)src)[0];
  float4 c = ((const float4*)src)[1];
  half8 h;
  h[0] = (_Float16)a.x; h[1] = (_Float16)a.y; h[2] = (_Float16)a.z; h[3] = (_Float16)a.w;
  h[4] = (_Float16)c.x; h[5] = (_Float16)c.y; h[6] = (_Float16)c.z; h[7] = (_Float16)c.w;
  *(half8*)(dst + (size_t)Y * HG * 524288 + base) = h;
}

// ---------------------------------------------------------------------------
template <int HG>
static void run_pipeline(const float* q_in, const float* k_in, const float* v_in,
                         const float* Wq, const float* Wk, const float* Wv,
                         const float* Wo, const float* bo, float* out, char* ws,
                         hipStream_t stream) {
  const int NG = 8 / HG;
  const long zc = 8 * HG;
  _Float16* W16 = (_Float16*)ws;                 // 8,388,608
  _Float16* in16 = W16 + 8388608;                // 3*HG*524288
  _Float16* Qp = in16 + 3L * HG * 524288;        // zc*524288 each
  _Float16* Kp = Qp + zc * 524288;
  _Float16* VWo = Kp + zc * 524288;
  _Float16* E = VWo + zc * 524288;               // zc*1048576
  _Float16* Vp = E;  // overlay: VWo dispatch (reads Vp) completes before
                     // energy dispatch (writes E) -- stream-ordered.
  _Float16* Wo16 = W16 + 3 * 2097152;
  dim3 blk(256);

  wbconv<<<dim3(8192), blk, 0, stream>>>(Wq, Wk, Wv, Wo, W16, out, bo);

  constexpr int HL = (HG >= 2) ? 2 : 1;
  constexpr int YS = HG / HL;

  for (int g = 0; g < NG; g++) {
    inconv<HG><<<dim3(HG * 256, 3), blk, 0, stream>>>(
        q_in + (size_t)g * HG * 65536, k_in + (size_t)g * HG * 65536,
        v_in + (size_t)g * HG * 65536, in16);

    proj_kernel<HG><<<dim3(HG * 32, 3, 8), blk, 0, stream>>>(in16, W16, Qp, Kp, Vp);

    vwo_kernel<HG><<<dim3(32, HG, 8), blk, 0, stream>>>(
        Vp, Wo16 + (size_t)g * HG * 512, VWo);

    energy_kernel<HG><<<dim3(36, HG, 8), blk, 0, stream>>>(Qp, Kp, E);

    softmax_rows<<<dim3(zc * 256), blk, 0, stream>>>(E);

    pv_kernel<HG, HL><<<dim3(32, YS, 8), blk, 0, stream>>>(E, VWo, out);
  }
}

extern "C" void kernel_launch(void* const* d_in, const int* in_sizes, int n_in,
                              void* d_out, int out_size, void* d_ws, size_t ws_size,
                              hipStream_t stream) {
  // setup_inputs order: k, v, q, mask, Wk, Wq, Wv, Wo, bo   (fp32)
  const float* k_in = (const float*)d_in[0];
  const float* v_in = (const float*)d_in[1];
  const float* q_in = (const float*)d_in[2];
  // d_in[3] = mask: exact causal tril, handled analytically
  const float* Wk = (const float*)d_in[4];
  const float* Wq = (const float*)d_in[5];
  const float* Wv = (const float*)d_in[6];
  const float* Wo = (const float*)d_in[7];
  const float* bo = (const float*)d_in[8];
  float* out = (float*)d_out;
  char* ws = (char*)d_ws;

  // exact footprints: HG=4 -> 197,132,288 B; HG=2 -> 106,954,752; HG=1 -> 61,865,984
  if (ws_size >= (size_t)197132288)
    run_pipeline<4>(q_in, k_in, v_in, Wq, Wk, Wv, Wo, bo, out, ws, stream);
  else if (ws_size >= (size_t)106954752)
    run_pipeline<2>(q_in, k_in, v_in, Wq, Wk, Wv, Wo, bo, out, ws, stream);
  else
    run_pipeline<1>(q_in, k_in, v_in, Wq, Wk, Wv, Wo, bo, out, ws, stream);
}